// Round 1
// baseline (108.651 us; speedup 1.0000x reference)
//
#include <hip/hip_runtime.h>
#include <math.h>

// Problem dims (fixed by setup_inputs): B=8, N=1024 -> ROWS=8192; M=2048; E=256; H1=32; H2=16
#define ROWS 8192
#define M_TOTAL 2048
#define E_DIM 256
#define H1 32
#define H2 16

__device__ __forceinline__ float gelu_exact(float x) {
    // jax.nn.gelu(approximate=False): x * 0.5 * (1 + erf(x/sqrt(2)))
    return 0.5f * x * (1.0f + erff(x * 0.70710678118654752f));
}

// One block per (b,n) row. 256 threads.
//   Phase 0: preload z/mu, compute the 8 d2 values per thread (hides z latency under MLP)
//   Phase 1: per-row sigma MLP, all 256 threads on layer-1 (32-way K-split, 4 outputs/thread,
//            float4 global loads of emb and w1 -> L1-hot, no LDS staging of inputs)
//   Phase 2: out[m] = exp(d2[m] * c), float4 stores (write-bound part)
__global__ __launch_bounds__(256) void fused_rbf(
    const float* __restrict__ z, const float* __restrict__ mu,
    const float* __restrict__ emb,
    const float* __restrict__ w1, const float* __restrict__ b1,
    const float* __restrict__ w2, const float* __restrict__ b2,
    const float* __restrict__ w3, const float* __restrict__ b3,
    float* __restrict__ out)
{
    __shared__ __align__(16) float sh1p[32 * 32];  // layer-1 partials [kg][o], 4 KB
    __shared__ float sh1[H1];
    __shared__ float sh2[H2];
    __shared__ float sc;

    const int t = threadIdx.x;
    const int row = blockIdx.x;

    // ---- Phase 0: z/mu loads + d2 (independent of the MLP; overlaps its latency) ----
    const float mu0 = mu[row * 2 + 0];
    const float mu1 = mu[row * 2 + 1];
    const float4* zf4 = (const float4*)z;          // z[M][2]: float4 j = (z[2j][.], z[2j+1][.])
    float d2[8];
    #pragma unroll
    for (int i = 0; i < 2; ++i) {
        const int idx = i * 256 + t;               // float4 index within the row: 0..511
        const float4 za = zf4[idx * 2 + 0];        // m = 4*idx + {0,1}
        const float4 zb = zf4[idx * 2 + 1];        // m = 4*idx + {2,3}
        float a, b;
        a = za.x - mu0; b = za.y - mu1; d2[i * 4 + 0] = fmaf(b, b, a * a);
        a = za.z - mu0; b = za.w - mu1; d2[i * 4 + 1] = fmaf(b, b, a * a);
        a = zb.x - mu0; b = zb.y - mu1; d2[i * 4 + 2] = fmaf(b, b, a * a);
        a = zb.z - mu0; b = zb.w - mu1; d2[i * 4 + 3] = fmaf(b, b, a * a);
    }

    // ---- Phase 1: layer 1 (256 -> 32). thread = (og = t&7 -> outputs og*4..og*4+3,
    //      kg = t>>3 -> k in [kg*8, kg*8+8)). All loads are coalesced float4 from global. ----
    {
        const int og = t & 7;
        const int kg = t >> 3;
        const float4* e4 = (const float4*)(emb + (size_t)row * E_DIM);
        const float4 e0 = e4[kg * 2 + 0];
        const float4 e1 = e4[kg * 2 + 1];
        const float ev[8] = {e0.x, e0.y, e0.z, e0.w, e1.x, e1.y, e1.z, e1.w};
        const float4* w14 = (const float4*)w1;     // w1[k][o]: row k = 8 float4
        float4 p = make_float4(0.f, 0.f, 0.f, 0.f);
        #pragma unroll
        for (int kk = 0; kk < 8; ++kk) {
            const float4 w = w14[(kg * 8 + kk) * 8 + og];
            p.x = fmaf(ev[kk], w.x, p.x);
            p.y = fmaf(ev[kk], w.y, p.y);
            p.z = fmaf(ev[kk], w.z, p.z);
            p.w = fmaf(ev[kk], w.w, p.w);
        }
        // flat float index kg*32 + og*4 + c == t*4 + c -> one conflict-free b128 store
        ((float4*)sh1p)[t] = p;
    }
    __syncthreads();

    // ---- wave 0 only: reduce + gelu, layer 2, layer 3 (intra-wave ordering, no syncs) ----
    if (t < H1) {
        float a = 0.f;
        #pragma unroll
        for (int kg = 0; kg < 32; ++kg) a += sh1p[kg * 32 + t];   // lane-stride-1: conflict-free
        sh1[t] = gelu_exact(a + b1[t]);
    }
    if (t < H2) {
        // sh1 written by lanes 0..31 of this same wave -> program order guarantees visibility
        float a = 0.f;
        #pragma unroll
        for (int k = 0; k < H1; ++k) a = fmaf(sh1[k], w2[k * H2 + t], a);
        sh2[t] = gelu_exact(a + b2[t]);
    }
    if (t == 0) {
        float s = 0.f;
        #pragma unroll
        for (int k = 0; k < H2; ++k) s = fmaf(sh2[k], w3[k], s);
        const float x = s + b3[0];
        const float sig = 1.0f / (1.0f + __expf(-x));
        const float sigma = 0.1f + 9.9f * sig;
        sc = -0.5f / (sigma * sigma);
    }
    __syncthreads();

    // ---- Phase 2: RBF evaluate + coalesced float4 stores ----
    const float c = sc;
    float4* out4 = (float4*)out + (size_t)row * (M_TOTAL / 4);
    #pragma unroll
    for (int i = 0; i < 2; ++i) {
        const int idx = i * 256 + t;
        float4 r;
        r.x = __expf(d2[i * 4 + 0] * c);
        r.y = __expf(d2[i * 4 + 1] * c);
        r.z = __expf(d2[i * 4 + 2] * c);
        r.w = __expf(d2[i * 4 + 3] * c);
        out4[idx] = r;                             // coalesced 16B stores
    }
}

extern "C" void kernel_launch(void* const* d_in, const int* in_sizes, int n_in,
                              void* d_out, int out_size, void* d_ws, size_t ws_size,
                              hipStream_t stream) {
    const float* z   = (const float*)d_in[0];
    const float* mu  = (const float*)d_in[1];
    const float* emb = (const float*)d_in[2];
    const float* w1  = (const float*)d_in[3];
    const float* b1  = (const float*)d_in[4];
    const float* w2  = (const float*)d_in[5];
    const float* b2  = (const float*)d_in[6];
    const float* w3  = (const float*)d_in[7];
    const float* b3  = (const float*)d_in[8];
    float* out = (float*)d_out;

    fused_rbf<<<ROWS, 256, 0, stream>>>(z, mu, emb, w1, b1, w2, b2, w3, b3, out);
}

// Round 2
// 99.235 us; speedup vs baseline: 1.0949x; 1.0949x over previous
//
#include <hip/hip_runtime.h>
#include <math.h>

// Problem dims (fixed by setup_inputs): B=8, N=1024 -> ROWS=8192; M=2048; E=256; H1=32; H2=16
#define ROWS 8192
#define M_TOTAL 2048
#define E_DIM 256
#define H1 32
#define H2 16
#define R_PER_BLK 8
#define NBLK (ROWS / R_PER_BLK)   // 1024 blocks = 4 per CU

__device__ __forceinline__ float gelu_exact(float x) {
    // jax.nn.gelu(approximate=False): x * 0.5 * (1 + erf(x/sqrt(2)))
    return 0.5f * x * (1.0f + erff(x * 0.70710678118654752f));
}

// One block per 8 rows. 256 threads.
//  - z (8 m-values/thread) loaded ONCE into regs, reused by all 8 rows.
//  - w1 chunk loaded ONCE into regs (8 float4/thread), reused by all 8 rows:
//    thread = (og = t&7 -> outputs og*4..+3, kg = t>>3 -> k in [kg*8, kg*8+8)).
//  - per row: 2 emb float4 loads + 32 FMA -> float4 partial -> LDS.
//  - reduce -> gelu -> layer2 -> layer3 -> sigma -> c per row.
//  - store phase: 8 rows x 2 float4 stores per thread (write-bound part).
__global__ __launch_bounds__(256) void fused_rbf_r8(
    const float* __restrict__ z, const float* __restrict__ mu,
    const float* __restrict__ emb,
    const float* __restrict__ w1, const float* __restrict__ b1,
    const float* __restrict__ w2, const float* __restrict__ b2,
    const float* __restrict__ w3, const float* __restrict__ b3,
    float* __restrict__ out)
{
    // layer-1 partials: [r][kg][o(32)+pad4] -> stride 36 floats.
    //  - b128 writes at kg*36+og*4: bank-quad = (kg+og)&7, balanced (8 lanes/quad = saturation, no excess)
    //  - reduce reads at g*36+o: bank = (4g+o)&31, distinct across lanes o=0..31 -> conflict-free
    __shared__ __align__(16) float part[R_PER_BLK * 32 * 36];   // 36 KB
    __shared__ float sh1[R_PER_BLK * 33];                       // pad 33: layer-2 reads conflict-free
    __shared__ float sh2[R_PER_BLK * 17];
    __shared__ float sc[R_PER_BLK];

    const int t = threadIdx.x;
    const int row0 = blockIdx.x * R_PER_BLK;

    // ---- z in registers: idx0 = t, idx1 = 256+t (float4 index within a row of 512) ----
    const float4* z4 = (const float4*)z;           // z[M][2]: float4 j = (z[2j][.], z[2j+1][.])
    const float4 za0 = z4[(size_t)t * 2 + 0];
    const float4 zb0 = z4[(size_t)t * 2 + 1];
    const float4 za1 = z4[(size_t)(256 + t) * 2 + 0];
    const float4 zb1 = z4[(size_t)(256 + t) * 2 + 1];

    // ---- w1 chunk in registers (loaded once per block) ----
    const int og = t & 7;
    const int kg = t >> 3;
    const float4* w14 = (const float4*)w1;         // w1[k][o]: row k = 8 float4
    float4 w[8];
    #pragma unroll
    for (int kk = 0; kk < 8; ++kk) w[kk] = w14[(kg * 8 + kk) * 8 + og];

    // ---- layer 1 partials for all 8 rows ----
    #pragma unroll
    for (int r = 0; r < R_PER_BLK; ++r) {
        const float4* e4 = (const float4*)(emb + (size_t)(row0 + r) * E_DIM);
        const float4 e0 = e4[kg * 2 + 0];
        const float4 e1 = e4[kg * 2 + 1];
        const float ev[8] = {e0.x, e0.y, e0.z, e0.w, e1.x, e1.y, e1.z, e1.w};
        float4 p = make_float4(0.f, 0.f, 0.f, 0.f);
        #pragma unroll
        for (int kk = 0; kk < 8; ++kk) {
            p.x = fmaf(ev[kk], w[kk].x, p.x);
            p.y = fmaf(ev[kk], w[kk].y, p.y);
            p.z = fmaf(ev[kk], w[kk].z, p.z);
            p.w = fmaf(ev[kk], w[kk].w, p.w);
        }
        *(float4*)&part[r * (32 * 36) + kg * 36 + og * 4] = p;
    }
    __syncthreads();

    // ---- reduce 32 kg-partials -> +b1 -> gelu -> sh1. 256 threads = 8 rows x 32 outputs ----
    {
        const int r = t >> 5;
        const int o = t & 31;
        float a = 0.f;
        #pragma unroll
        for (int g = 0; g < 32; ++g) a += part[r * (32 * 36) + g * 36 + o];
        sh1[r * 33 + o] = gelu_exact(a + b1[o]);
    }
    __syncthreads();

    // ---- wave 0: layer 2 (8 rows x 16 outs over 2 iters), then layer 3 (8 lanes).
    //      Intra-wave LDS write->read is in-order; no barrier needed inside. ----
    if (t < 64) {
        #pragma unroll
        for (int h = 0; h < 2; ++h) {
            const int r = (t >> 4) + 4 * h;
            const int o2 = t & 15;
            float a = 0.f;
            #pragma unroll
            for (int k = 0; k < H1; ++k) a = fmaf(sh1[r * 33 + k], w2[k * H2 + o2], a);
            sh2[r * 17 + o2] = gelu_exact(a + b2[o2]);
        }
        if (t < R_PER_BLK) {
            float s = 0.f;
            #pragma unroll
            for (int k = 0; k < H2; ++k) s = fmaf(sh2[t * 17 + k], w3[k], s);
            const float x = s + b3[0];
            const float sig = 1.0f / (1.0f + __expf(-x));
            const float sigma = 0.1f + 9.9f * sig;
            sc[t] = -0.5f / (sigma * sigma);
        }
    }
    __syncthreads();

    // ---- store phase: 8 rows x (8 exp + 2 float4 stores) per thread ----
    #pragma unroll
    for (int r = 0; r < R_PER_BLK; ++r) {
        const float c = sc[r];
        const float mu0 = mu[(size_t)(row0 + r) * 2 + 0];   // uniform -> scalarized by compiler
        const float mu1 = mu[(size_t)(row0 + r) * 2 + 1];
        float4* out4 = (float4*)out + (size_t)(row0 + r) * (M_TOTAL / 4);
        float a, b;
        float4 r0, r1;
        a = za0.x - mu0; b = za0.y - mu1; r0.x = __expf(fmaf(b, b, a * a) * c);
        a = za0.z - mu0; b = za0.w - mu1; r0.y = __expf(fmaf(b, b, a * a) * c);
        a = zb0.x - mu0; b = zb0.y - mu1; r0.z = __expf(fmaf(b, b, a * a) * c);
        a = zb0.z - mu0; b = zb0.w - mu1; r0.w = __expf(fmaf(b, b, a * a) * c);
        a = za1.x - mu0; b = za1.y - mu1; r1.x = __expf(fmaf(b, b, a * a) * c);
        a = za1.z - mu0; b = za1.w - mu1; r1.y = __expf(fmaf(b, b, a * a) * c);
        a = zb1.x - mu0; b = zb1.y - mu1; r1.z = __expf(fmaf(b, b, a * a) * c);
        a = zb1.z - mu0; b = zb1.w - mu1; r1.w = __expf(fmaf(b, b, a * a) * c);
        out4[t] = r0;                              // coalesced 16B stores
        out4[256 + t] = r1;
    }
}

extern "C" void kernel_launch(void* const* d_in, const int* in_sizes, int n_in,
                              void* d_out, int out_size, void* d_ws, size_t ws_size,
                              hipStream_t stream) {
    const float* z   = (const float*)d_in[0];
    const float* mu  = (const float*)d_in[1];
    const float* emb = (const float*)d_in[2];
    const float* w1  = (const float*)d_in[3];
    const float* b1  = (const float*)d_in[4];
    const float* w2  = (const float*)d_in[5];
    const float* b2  = (const float*)d_in[6];
    const float* w3  = (const float*)d_in[7];
    const float* b3  = (const float*)d_in[8];
    float* out = (float*)d_out;

    fused_rbf_r8<<<NBLK, 256, 0, stream>>>(z, mu, emb, w1, b1, w2, b2, w3, b3, out);
}